// Round 19
// baseline (62.859 us; speedup 1.0000x reference)
//
#include <hip/hip_runtime.h>
#include <math.h>

// out[b,oc,y,x] = max_t min(p_t, k_t), p = channel-max(32) of x, OOB=-inf.
// x (16,32,256,256) f32, k (32,5,5) f32, out (16,32,256,256) f32.
//
// Split with halo-on-xm (byte floor ~275MB):
//  sort: rank taps per oc descending (exact; ties by index).
//  A: chanmax x -> xm (134MB read / 4MB write), 16-deep load batches.
//  B: BARRIER-FREE wave-autonomous conv: wave = 32x8 tile; stage 12x40 xm
//     halo into private LDS slice (L2 reads, ~7MB total); lgkmcnt-only sync;
//     32-oc sorted early-exit scan; nt-store write stream 131MB.
//  r18 bug fixed: window col base needs +2 (halo origin = tx*32-4; out col
//  4xg+j, tap dx -> LDS col 4xg+j+dx+2).

#define BATCH 16
#define CH    32
#define OCH   32
#define HH    256
#define WW    256
#define HWSZ  (HH * WW)
#define LH    12              // 8 + 4 halo rows
#define LW    44              // 40 data cols + 4 pad (16B-aligned granules)
#define NWGB  1024            // 4096 wave-tiles / 4 waves per block

typedef float floatx4 __attribute__((ext_vector_type(4)));

// ---- Kernel 0: rank taps (descending k), one block ----
__global__ void sort_taps_kernel(const float* __restrict__ kk, float2* __restrict__ ent) {
    int t = threadIdx.x;
    if (t >= OCH * 25) return;
    int oc = t / 25, i = t % 25;
    float ki = kk[oc * 25 + i];
    int rank = 0;
#pragma unroll
    for (int j = 0; j < 25; ++j) {
        float kj = kk[oc * 25 + j];
        rank += (kj > ki) || (kj == ki && j < i);
    }
    int dy = i / 5, dx = i % 5;
    int off = 4 * (dy * LW + dx);                 // byte offset in private slice
    ent[oc * 26 + rank] = make_float2(ki, __int_as_float(off));
    if (i == 0) ent[oc * 26 + 25] = make_float2(-INFINITY, __int_as_float(0));
}

// ---- Kernel A: channel max, 16-deep load batches, fully coalesced ----
__global__ __launch_bounds__(256) void chanmax_kernel(const float* __restrict__ x,
                                                      float* __restrict__ xm) {
    int i4 = blockIdx.x * blockDim.x + threadIdx.x;   // 0 .. 262143
    int b  = i4 >> 14;
    int r  = i4 & 16383;
    const float4* base = (const float4*)x + (size_t)b * (CH * (HWSZ / 4)) + r;

    float4 v[16];
#pragma unroll
    for (int j = 0; j < 16; ++j) v[j] = base[(size_t)j * (HWSZ / 4)];
    float4 m = v[0];
#pragma unroll
    for (int j = 1; j < 16; ++j) {
        m.x = fmaxf(m.x, v[j].x); m.y = fmaxf(m.y, v[j].y);
        m.z = fmaxf(m.z, v[j].z); m.w = fmaxf(m.w, v[j].w);
    }
#pragma unroll
    for (int j = 0; j < 16; ++j) v[j] = base[(size_t)(16 + j) * (HWSZ / 4)];
#pragma unroll
    for (int j = 0; j < 16; ++j) {
        m.x = fmaxf(m.x, v[j].x); m.y = fmaxf(m.y, v[j].y);
        m.z = fmaxf(m.z, v[j].z); m.w = fmaxf(m.w, v[j].w);
    }
    ((float4*)xm)[i4] = m;
}

// ---- Kernel B: wave-autonomous early-exit conv from xm ----
__global__ __launch_bounds__(256, 2) void conv_kernel(const float* __restrict__ xm,
                                                      const float2* __restrict__ gent,
                                                      float* __restrict__ out) {
    __shared__ float xs[4][LH][LW];        // per-wave private slices
    __shared__ float2 ent[OCH * 26];
    int tid  = threadIdx.x;
    int wv   = tid >> 6;
    int lane = tid & 63;
    int bid  = blockIdx.x;
    int swz  = (bid & 7) * (NWGB >> 3) + (bid >> 3);  // XCD-chunked, bijective
    int tile = swz * 4 + wv;                          // 0..4095
    int b    = tile >> 8;
    int t2   = tile & 255;
    int ty   = t2 >> 3;                               // 0..31 (8-row bands)
    int tx   = t2 & 7;                                // 0..7  (32-col bands)

    const float NI = -INFINITY;

    // taps -> LDS (one barrier, before heavy work; waves free-run after)
    for (int i = tid; i < OCH * 26; i += 256) ent[i] = gent[i];
    __syncthreads();

    // ---- stage private slice: 120 granules (12 rows x 10 float4) ----
    float* Ls = &xs[wv][0][0];
    const float4* xb4 = (const float4*)xm + (size_t)b * (HWSZ / 4);
#pragma unroll
    for (int gi = 0; gi < 2; ++gi) {
        int g = lane + 64 * gi;
        if (g < 120) {
            int pr = g / 10, pc = g % 10;
            int c4 = tx * 8 - 1 + pc;
            int rw = ty * 8 - 2 + pr;
            bool valid = (c4 >= 0) && (c4 < WW / 4) && (rw >= 0) && (rw < HH);
            int c4c = c4 < 0 ? 0 : (c4 > WW / 4 - 1 ? WW / 4 - 1 : c4);
            int rwc = rw < 0 ? 0 : (rw > HH - 1 ? HH - 1 : rw);
            float4 m = xb4[(size_t)rwc * (WW / 4) + c4c];
            if (!valid) { m.x = NI; m.y = NI; m.z = NI; m.w = NI; }
            *(float4*)(Ls + pr * LW + 4 * pc) = m;
        }
    }
    asm volatile("s_waitcnt lgkmcnt(0)" ::: "memory");   // wave-coherent only

    // ---- 32-oc sorted early-exit scan; lane = 4 px x 1 row ----
    int xg = lane & 7;
    int rw = lane >> 3;
    const char* wbase = (const char*)(Ls + rw * LW + 4 * xg + 2);   // +2: halo origin
    size_t obase = (size_t)b * OCH * HWSZ + (size_t)(ty * 8 + rw) * WW
                 + tx * 32 + 4 * xg;

    for (int o = 0; o < OCH; ++o) {
        const float2* E = &ent[o * 26];
        float a0 = NI, a1 = NI, a2 = NI, a3 = NI;
        for (int i = 0; i < 25; ++i) {
            float2 e  = E[i];                        // uniform -> LDS broadcast
            float  kn = E[i + 1].x;
            float  kv = e.x;
            const float* p = (const float*)(wbase + __float_as_int(e.y));
            a0 = fmaxf(a0, fminf(p[0], kv));
            a1 = fmaxf(a1, fminf(p[1], kv));
            a2 = fmaxf(a2, fminf(p[2], kv));
            a3 = fmaxf(a3, fminf(p[3], kv));
            float mn = fminf(fminf(a0, a1), fminf(a2, a3));
            if (__all(mn >= kn)) break;              // remaining cands <= kn <= a
        }
        floatx4 ov = { a0, a1, a2, a3 };
        __builtin_nontemporal_store(ov, (floatx4*)(out + obase + (size_t)o * HWSZ));
    }
}

extern "C" void kernel_launch(void* const* d_in, const int* in_sizes, int n_in,
                              void* d_out, int out_size, void* d_ws, size_t ws_size,
                              hipStream_t stream) {
    const float* x  = (const float*)d_in[0];
    const float* kk = (const float*)d_in[1];
    float* out      = (float*)d_out;
    float2* ent     = (float2*)d_ws;                       // 6656 B
    float*  xm      = (float*)((char*)d_ws + 8192);        // 4 MB

    sort_taps_kernel<<<1, OCH * 25, 0, stream>>>(kk, ent);
    chanmax_kernel<<<BATCH * HWSZ / 4 / 256, 256, 0, stream>>>(x, xm);
    conv_kernel<<<NWGB, 256, 0, stream>>>(xm, ent, out);
}